// Round 12
// baseline (467.463 us; speedup 1.0000x reference)
//
#include <hip/hip_runtime.h>
#include <hip/hip_bf16.h>

typedef __bf16 bf16x8 __attribute__((ext_vector_type(8)));
typedef float  f32x4  __attribute__((ext_vector_type(4)));

#define N_TOT   16384
#define K_TOT   16384
#define HALF_M  ((size_t)128 * 16384)
#define BN      256
#define BK      64
#define KSPLIT  4
#define KQ_LEN  (K_TOT / KSPLIT)      // 4096
#define NQSTEPS (KQ_LEN / BK)         // 64
#define OUT_ELEMS ((size_t)256 * 16384)

__device__ __forceinline__ unsigned short f2bf(float f) {
    __hip_bfloat16 h = __float2bfloat16(f);
    return __builtin_bit_cast(unsigned short, h);
}

// Swizzled byte offset: 128-B rows, 16-B granules, XOR row&7 into granule idx.
__device__ __forceinline__ int swz(int row, int g) {
    return row * 128 + (((g ^ (row & 7)) & 7) << 4);
}

// One-time T = concat(x0,x1) fp32 -> bf16 into workspace (linear row-major).
__global__ void cvtT_kernel(const float* __restrict__ x0,
                            const float* __restrict__ x1,
                            unsigned short* __restrict__ wsT) {
    size_t i = (size_t)blockIdx.x * blockDim.x + threadIdx.x;  // 0..524287
    size_t e = i * 8;
    const float* src = (e < HALF_M) ? (x0 + e) : (x1 + (e - HALF_M));
    float4 a = ((const float4*)src)[0];
    float4 b = ((const float4*)src)[1];
    union { unsigned short u[8]; uint4 v; } o;
    o.u[0] = f2bf(a.x); o.u[1] = f2bf(a.y); o.u[2] = f2bf(a.z); o.u[3] = f2bf(a.w);
    o.u[4] = f2bf(b.x); o.u[5] = f2bf(b.y); o.u[6] = f2bf(b.z); o.u[7] = f2bf(b.w);
    ((uint4*)wsT)[i] = o.v;
}

// out += p0 + p1 + p2 (fixed order -> deterministic)
__global__ void combine_kernel(float* __restrict__ out,
                               const float* __restrict__ p0,
                               const float* __restrict__ p1,
                               const float* __restrict__ p2) {
    const size_t n4 = OUT_ELEMS / 4;
    size_t i = (size_t)blockIdx.x * blockDim.x + threadIdx.x;
    for (; i < n4; i += (size_t)gridDim.x * blockDim.x) {
        float4 o = ((const float4*)out)[i];
        float4 a = ((const float4*)p0)[i];
        float4 b = ((const float4*)p1)[i];
        float4 c = ((const float4*)p2)[i];
        o.x += a.x + b.x + c.x;  o.y += a.y + b.y + c.y;
        o.z += a.z + b.z + c.z;  o.w += a.w + b.w + c.w;
        ((float4*)out)[i] = o;
    }
}

// ---- single-set prefetch (issued >= 1 full step (~5000 cy) before use) ----
// A: thread covers 32 B of its wsT row; W: 16 fp32 (64 B) of its W row.
#define ISSUE(k0) do {                                                        \
    const uint4* _p = (const uint4*)(arow_w + (k0));                          \
    aR0 = _p[0]; aR1 = _p[1];                                                 \
    const f32x4* _q = (const f32x4*)(brow + (k0));                            \
    wR0 = _q[0]; wR1 = _q[1]; wR2 = _q[2]; wR3 = _q[3];                       \
} while (0)

#define STAGE(Ab, Bb) do {                                                    \
    *(uint4*)((Ab) + aw0) = aR0;                                              \
    *(uint4*)((Ab) + aw1) = aR1;                                              \
    union { unsigned short u[8]; uint4 v; } _t0, _t1;                         \
    _t0.u[0]=f2bf(wR0[0]); _t0.u[1]=f2bf(wR0[1]);                             \
    _t0.u[2]=f2bf(wR0[2]); _t0.u[3]=f2bf(wR0[3]);                             \
    _t0.u[4]=f2bf(wR1[0]); _t0.u[5]=f2bf(wR1[1]);                             \
    _t0.u[6]=f2bf(wR1[2]); _t0.u[7]=f2bf(wR1[3]);                             \
    _t1.u[0]=f2bf(wR2[0]); _t1.u[1]=f2bf(wR2[1]);                             \
    _t1.u[2]=f2bf(wR2[2]); _t1.u[3]=f2bf(wR2[3]);                             \
    _t1.u[4]=f2bf(wR3[0]); _t1.u[5]=f2bf(wR3[1]);                             \
    _t1.u[6]=f2bf(wR3[2]); _t1.u[7]=f2bf(wR3[3]);                             \
    *(uint4*)((Bb) + bw0) = _t0.v;                                            \
    *(uint4*)((Bb) + bw1) = _t1.v;                                            \
} while (0)

// One K-half (kf): 4 A-frag reads held, B-frags read one at a time.
// Live transients: 4 x bf16x8 (A) + 1 x bf16x8 (B) = 20 VGPR.
#define COMPUTE_HALF(Ab, Bb, AOFF, BOFF) do {                                 \
    bf16x8 _a0 = *(const bf16x8*)((Ab) + (AOFF) + 0*2048);                    \
    bf16x8 _a1 = *(const bf16x8*)((Ab) + (AOFF) + 1*2048);                    \
    bf16x8 _a2 = *(const bf16x8*)((Ab) + (AOFF) + 2*2048);                    \
    bf16x8 _a3 = *(const bf16x8*)((Ab) + (AOFF) + 3*2048);                    \
    bf16x8 _bv;                                                               \
    _bv = *(const bf16x8*)((Bb) + (BOFF) + 0*2048);                           \
    acc00 = __builtin_amdgcn_mfma_f32_16x16x32_bf16(_a0, _bv, acc00, 0,0,0);  \
    acc10 = __builtin_amdgcn_mfma_f32_16x16x32_bf16(_a1, _bv, acc10, 0,0,0);  \
    acc20 = __builtin_amdgcn_mfma_f32_16x16x32_bf16(_a2, _bv, acc20, 0,0,0);  \
    acc30 = __builtin_amdgcn_mfma_f32_16x16x32_bf16(_a3, _bv, acc30, 0,0,0);  \
    _bv = *(const bf16x8*)((Bb) + (BOFF) + 1*2048);                           \
    acc01 = __builtin_amdgcn_mfma_f32_16x16x32_bf16(_a0, _bv, acc01, 0,0,0);  \
    acc11 = __builtin_amdgcn_mfma_f32_16x16x32_bf16(_a1, _bv, acc11, 0,0,0);  \
    acc21 = __builtin_amdgcn_mfma_f32_16x16x32_bf16(_a2, _bv, acc21, 0,0,0);  \
    acc31 = __builtin_amdgcn_mfma_f32_16x16x32_bf16(_a3, _bv, acc31, 0,0,0);  \
    _bv = *(const bf16x8*)((Bb) + (BOFF) + 2*2048);                           \
    acc02 = __builtin_amdgcn_mfma_f32_16x16x32_bf16(_a0, _bv, acc02, 0,0,0);  \
    acc12 = __builtin_amdgcn_mfma_f32_16x16x32_bf16(_a1, _bv, acc12, 0,0,0);  \
    acc22 = __builtin_amdgcn_mfma_f32_16x16x32_bf16(_a2, _bv, acc22, 0,0,0);  \
    acc32 = __builtin_amdgcn_mfma_f32_16x16x32_bf16(_a3, _bv, acc32, 0,0,0);  \
    _bv = *(const bf16x8*)((Bb) + (BOFF) + 3*2048);                           \
    acc03 = __builtin_amdgcn_mfma_f32_16x16x32_bf16(_a0, _bv, acc03, 0,0,0);  \
    acc13 = __builtin_amdgcn_mfma_f32_16x16x32_bf16(_a1, _bv, acc13, 0,0,0);  \
    acc23 = __builtin_amdgcn_mfma_f32_16x16x32_bf16(_a2, _bv, acc23, 0,0,0);  \
    acc33 = __builtin_amdgcn_mfma_f32_16x16x32_bf16(_a3, _bv, acc33, 0,0,0);  \
} while (0)

// 16 waves as 4M x 4N over 256M x 256N: wave owns 64M x 64N.
// 8 A-reads + 8 B-reads + 32 MFMA per step (kf=0 then kf=1 via ^64).
#define COMPUTE(Ab, Bb) do {                                                  \
    COMPUTE_HALF(Ab, Bb, aK0, bK0);                                           \
    COMPUTE_HALF(Ab, Bb, aK1, bK1);                                           \
} while (0)

#define SYNC do {                                                             \
    asm volatile("s_waitcnt lgkmcnt(0)" ::: "memory");                        \
    __builtin_amdgcn_s_barrier();                                             \
    __builtin_amdgcn_sched_barrier(0);                                        \
} while (0)

// GEMM: grid 256 = 64 n-strips x 4 kq (kq=bid>>6). BN=256: A-traffic halves
// vs BN=128 (total A bytes = nstrips x 8.4 MB), and per-step W (64 KB/CU,
// ~6400 cy) doubles -> per-step overhead fraction halves. LDS 128 KiB.
__global__ __launch_bounds__(1024, 4)
void gemm_ws(const float* __restrict__ W, const float* __restrict__ bias,
             const unsigned short* __restrict__ wsT,
             float* __restrict__ out, float* __restrict__ wsP)
{
    __shared__ uint4 smem_[(4 * 32768) / 16];  // 128 KiB
    char* const sm = (char*)smem_;
    char* const A0 = sm;                       // A: 256 rows x 128 B
    char* const A1 = sm + 32768;
    char* const B0 = sm + 65536;               // B: 256 rows x 128 B
    char* const B1 = sm + 65536 + 32768;

    const int tid  = threadIdx.x;
    const int lane = tid & 63;
    const int wave = tid >> 6;
    const int wm = wave >> 2;                  // 0..3 (64 M rows)
    const int wn = wave & 3;                   // 0..3 (64 N cols)
    const int bid    = blockIdx.x;
    const int kq     = bid >> 6;               // 0..3
    const int nstrip = bid & 63;
    const int n0     = nstrip * BN;
    const int kbase  = kq * KQ_LEN;

    // staging geometry: 4 threads per row for both A and B (rows 0..255)
    const int rr = tid >> 2;                   // row 0..255
    const int pp = tid & 3;                    // 32-B bf16 chunk (2 granules)

    const unsigned short* arow_w = wsT + (size_t)rr * K_TOT + kbase + pp * 16;
    const float* brow = W + (size_t)(n0 + rr) * K_TOT + kbase + pp * 16;

    const int aw0 = swz(rr, 2 * pp);
    const int aw1 = swz(rr, 2 * pp + 1);
    const int bw0 = aw0;                       // same swizzle pattern
    const int bw1 = aw1;

    // frag-read bases: XOR term invariant under mf/nf (+2048) ; kf flips ^64
    const int aK0 = swz(wm * 64 + (lane & 15), lane >> 4);
    const int aK1 = aK0 ^ 64;
    const int bK0 = swz(wn * 64 + (lane & 15), lane >> 4);
    const int bK1 = bK0 ^ 64;

    f32x4 acc00={0,0,0,0}, acc01={0,0,0,0}, acc02={0,0,0,0}, acc03={0,0,0,0};
    f32x4 acc10={0,0,0,0}, acc11={0,0,0,0}, acc12={0,0,0,0}, acc13={0,0,0,0};
    f32x4 acc20={0,0,0,0}, acc21={0,0,0,0}, acc22={0,0,0,0}, acc23={0,0,0,0};
    f32x4 acc30={0,0,0,0}, acc31={0,0,0,0}, acc32={0,0,0,0}, acc33={0,0,0,0};

    uint4 aR0, aR1;
    f32x4 wR0, wR1, wR2, wR3;

    // prologue
    ISSUE(0);
    STAGE(A0, B0);
    ISSUE(BK);                                 // step-1 loads fly over barrier
    SYNC;

    for (int kt = 0; kt < NQSTEPS; kt += 2) {
        // phase even: compute step kt; stage step kt+1; issue step kt+2
        COMPUTE(A0, B0);
        STAGE(A1, B1);
        if (kt + 2 < NQSTEPS) ISSUE((kt + 2) * BK);
        SYNC;
        // phase odd: compute step kt+1; stage step kt+2; issue step kt+3
        COMPUTE(A1, B1);
        if (kt + 2 < NQSTEPS) STAGE(A0, B0);
        if (kt + 3 < NQSTEPS) ISSUE((kt + 3) * BK);
        SYNC;
    }

    // epilogue: kq==0 writes bias+acc to out; kq>0 writes acc to partial buf.
    float* const dst = (kq == 0) ? out : (wsP + (size_t)(kq - 1) * OUT_ELEMS);
    #pragma unroll
    for (int nf = 0; nf < 4; ++nf) {
        const int col = n0 + wn * 64 + nf * 16 + (lane & 15);
        const float bv = (kq == 0) ? bias[col] : 0.f;
        #pragma unroll
        for (int mf = 0; mf < 4; ++mf) {
            const f32x4 a =
                (nf == 0) ? (mf==0?acc00:mf==1?acc10:mf==2?acc20:acc30) :
                (nf == 1) ? (mf==0?acc01:mf==1?acc11:mf==2?acc21:acc31) :
                (nf == 2) ? (mf==0?acc02:mf==1?acc12:mf==2?acc22:acc32) :
                            (mf==0?acc03:mf==1?acc13:mf==2?acc23:acc33);
            #pragma unroll
            for (int j = 0; j < 4; ++j) {
                int r = wm * 64 + mf * 16 + (lane >> 4) * 4 + j;
                float v = a[j] + bv;
                float* o = (r < 128) ? (dst + (size_t)r * N_TOT + col)
                                     : (dst + HALF_M + (size_t)(r - 128) * N_TOT + col);
                *o = v;
            }
        }
    }
}

extern "C" void kernel_launch(void* const* d_in, const int* in_sizes, int n_in,
                              void* d_out, int out_size, void* d_ws, size_t ws_size,
                              hipStream_t stream) {
    const float* x0 = (const float*)d_in[0];
    const float* x1 = (const float*)d_in[1];
    const float* W  = (const float*)d_in[2];
    const float* b  = (const float*)d_in[3];
    float* out = (float*)d_out;

    const size_t wsT_bytes = (size_t)256 * 16384 * sizeof(unsigned short);  // 8.4 MB

    unsigned short* wsT = (unsigned short*)d_ws;
    float* wsP = (float*)((char*)d_ws + wsT_bytes);

    cvtT_kernel<<<2048, 256, 0, stream>>>(x0, x1, wsT);
    gemm_ws<<<256, 1024, 0, stream>>>(W, b, wsT, out, wsP);
    combine_kernel<<<2048, 256, 0, stream>>>(out, wsP, wsP + OUT_ELEMS,
                                             wsP + 2 * OUT_ELEMS);
}